// Round 4
// baseline (31.646 us; speedup 1.0000x reference)
//
#include <hip/hip_runtime.h>

#define OUT 224
#define NIMG 64
#define NCH 3
#define IMH 1080
#define IMW 1920

// 4 output pixels per thread along x: OUT/4 = 56 thread-columns per row.
#define XV 4
#define OUTV (OUT / XV)
#define NXCD 8

__global__ __launch_bounds__(256) void roi_extract_v4_swz_kernel(
    const float* __restrict__ features,   // [N,C,H,W]
    const int4*  __restrict__ detections, // [N] {x1,y1,x2,y2}
    float4*      __restrict__ out,        // [N,C,OUT,OUT/4]
    int chunk)                            // gridDim.x / NXCD (exact)
{
    // XCD-aware swizzle: physical dispatch round-robins XCDs (slot i -> XCD i%8).
    // Map so each XCD gets a CONTIGUOUS chunk of logical work -> each image's
    // crop is fetched into exactly one XCD's L2 (kills 8x read amplification).
    const int bid = blockIdx.x;
    const int logical = (bid % NXCD) * chunk + bid / NXCD;

    const int idx = logical * blockDim.x + threadIdx.x;
    const int total = NIMG * NCH * OUT * OUTV;
    if (idx >= total) return;

    const int oxv = idx % OUTV;             // vector column
    const int oy  = (idx / OUTV) % OUT;
    const int c   = (idx / (OUTV * OUT)) % NCH;
    const int n   = idx / (OUTV * OUT * NCH);

    const int4 box = detections[n];
    const float bh = (float)(box.w - box.y);
    const float bw = (float)(box.z - box.x);
    const float fy1 = (float)box.y;
    const float fx1 = (float)box.x;

    // ---- y setup (shared by the 4 outputs) ----
    float ysf = ((float)oy + 0.5f) * bh * (1.0f / OUT) - 0.5f;
    ysf = fminf(fmaxf(ysf, 0.0f), bh - 1.0f) + fy1;
    const float y0f = floorf(ysf);
    const float wy  = ysf - y0f;
    int y0 = min(max((int)y0f, 0), IMH - 1);
    const int y1i = min(y0 + 1, IMH - 1);

    const float* __restrict__ base =
        features + ((size_t)n * NCH + c) * (size_t)(IMH * IMW);
    const float* __restrict__ row0 = base + (size_t)y0  * IMW;
    const float* __restrict__ row1 = base + (size_t)y1i * IMW;

    const int ox0 = oxv * XV;

    float res[XV];
#pragma unroll
    for (int j = 0; j < XV; ++j) {
        float xsf = ((float)(ox0 + j) + 0.5f) * bw * (1.0f / OUT) - 0.5f;
        xsf = fminf(fmaxf(xsf, 0.0f), bw - 1.0f) + fx1;
        const float x0f = floorf(xsf);
        const float wx  = xsf - x0f;
        int x0 = min(max((int)x0f, 0), IMW - 1);
        const int x1i = min(x0 + 1, IMW - 1);

        const float v00 = row0[x0];
        const float v01 = row0[x1i];
        const float v10 = row1[x0];
        const float v11 = row1[x1i];

        const float top = v00 + (v01 - v00) * wx;
        const float bot = v10 + (v11 - v10) * wx;
        res[j] = top + (bot - top) * wy;
    }

    out[idx] = make_float4(res[0], res[1], res[2], res[3]);
}

extern "C" void kernel_launch(void* const* d_in, const int* in_sizes, int n_in,
                              void* d_out, int out_size, void* d_ws, size_t ws_size,
                              hipStream_t stream) {
    const float* features   = (const float*)d_in[0];
    const int4*  detections = (const int4*)d_in[1];
    float4*      out        = (float4*)d_out;

    const int total = NIMG * NCH * OUT * OUTV;   // 2,408,448
    const int block = 256;
    const int grid  = (total + block - 1) / block; // 9408 = 8 * 1176 exactly
    const int chunk = grid / NXCD;
    roi_extract_v4_swz_kernel<<<grid, block, 0, stream>>>(features, detections, out, chunk);
}

// Round 5
// 25.115 us; speedup vs baseline: 1.2600x; 1.2600x over previous
//
#include <hip/hip_runtime.h>

#define OUT 224
#define NIMG 64
#define NCH 3
#define IMH 1080
#define IMW 1920

#define RG 4              // output rows per block (one per wave)
#define NGRP (OUT / RG)   // 56 row-groups
#define ROWP 324          // LDS row pitch (floats): max bw+1 = 321, padded
#define MAXR 8            // max staged source rows (bound: <=7)

__global__ __launch_bounds__(256) void roi_lds_kernel(
    const float* __restrict__ features,   // [N,C,H,W]
    const int4*  __restrict__ detections, // [N] {x1,y1,x2,y2}
    float*       __restrict__ out)        // [N,C,OUT,OUT]
{
    __shared__ float lds[MAXR * ROWP];

    const int bid = blockIdx.x;
    const int g = bid % NGRP;
    const int c = (bid / NGRP) % NCH;
    const int n = bid / (NGRP * NCH);
    const int oy0 = g * RG;

    const int4 box = detections[n];
    const float bh = (float)(box.w - box.y);
    const float bw = (float)(box.z - box.x);
    const int   bw1 = (box.z - box.x) + 1;   // staged floats per row

    // local (crop-relative) clamped source y for an output row
    auto ysrc = [&](int oy) -> float {
        float ys = ((float)oy + 0.5f) * bh * (1.0f / OUT) - 0.5f;
        return fminf(fmaxf(ys, 0.0f), bh - 1.0f);
    };

    const int yA = (int)floorf(ysrc(oy0));                 // first staged row
    const int yE = (int)floorf(ysrc(oy0 + RG - 1)) + 1;    // last staged row
    const int NR = yE - yA + 1;                            // <= 7

    const float* __restrict__ base =
        features + ((size_t)n * NCH + c) * (size_t)(IMH * IMW);

    // ---- stage NR source row segments [x1 .. x1+bw] into LDS (coalesced) ----
    // boxes are strictly in-bounds: x1+bw <= W-1, y1+bh <= H-1 (per setup).
    const int tid = threadIdx.x;
    const float* __restrict__ src0 =
        base + (size_t)(box.y + yA) * IMW + box.x;
    for (int r = 0; r < NR; ++r) {
        const float* __restrict__ src = src0 + (size_t)r * IMW;
        for (int x = tid; x < bw1; x += 256)
            lds[r * ROWP + x] = src[x];
    }
    __syncthreads();

    // ---- compute: wave w handles output row oy0+w ----
    const int wave = tid >> 6;
    const int lane = tid & 63;
    const int oy = oy0 + wave;

    const float ys  = ysrc(oy);
    const float y0f = floorf(ys);
    const float wy  = ys - y0f;
    const int   r0  = (int)y0f - yA;            // in [0, NR-2]
    const float* __restrict__ l0 = lds + r0 * ROWP;
    const float* __restrict__ l1 = l0 + ROWP;

    float* __restrict__ orow =
        out + (((size_t)n * NCH + c) * OUT + oy) * OUT;

#pragma unroll
    for (int k = 0; k < 4; ++k) {
        const int ox = lane + k * 64;
        if (ox < OUT) {
            float xs = ((float)ox + 0.5f) * bw * (1.0f / OUT) - 0.5f;
            xs = fminf(fmaxf(xs, 0.0f), bw - 1.0f);
            const float x0f = floorf(xs);
            const float wx  = xs - x0f;
            const int   ix  = (int)x0f;          // in [0, bw-1]; ix+1 <= bw staged
            const float v00 = l0[ix], v01 = l0[ix + 1];
            const float v10 = l1[ix], v11 = l1[ix + 1];
            const float top = v00 * (1.0f - wx) + v01 * wx;
            const float bot = v10 * (1.0f - wx) + v11 * wx;
            orow[ox] = top * (1.0f - wy) + bot * wy;
        }
    }
}

extern "C" void kernel_launch(void* const* d_in, const int* in_sizes, int n_in,
                              void* d_out, int out_size, void* d_ws, size_t ws_size,
                              hipStream_t stream) {
    const float* features   = (const float*)d_in[0];
    const int4*  detections = (const int4*)d_in[1];
    float*       out        = (float*)d_out;

    const int grid = NIMG * NCH * NGRP;   // 64*3*56 = 10752 blocks
    roi_lds_kernel<<<grid, 256, 0, stream>>>(features, detections, out);
}

// Round 6
// 20.736 us; speedup vs baseline: 1.5261x; 1.2112x over previous
//
#include <hip/hip_runtime.h>

#define OUT 224
#define NIMG 64
#define NCH 3
#define IMH 1080
#define IMW 1920

#define RG 8               // output rows per block (one per wave)
#define NGRP (OUT / RG)    // 28 row-groups
#define NW 8               // waves per block (512 threads)
#define ROWP 328           // LDS row pitch (floats): <=324 needed, mult of 4
#define MAXR 13            // max staged rows: ceil(7*319/224)+2 = 12, padded
#define NXCD 8

__global__ __launch_bounds__(512) void roi_lds8_kernel(
    const float* __restrict__ features,   // [N,C,H,W]
    const int4*  __restrict__ detections, // [N] {x1,y1,x2,y2}
    float4*      __restrict__ out)        // [N,C,OUT,OUT/4]
{
    __shared__ float lds[MAXR * ROWP];

    // chunked XCD swizzle: grid = 5376 = 8 * 672 exactly
    const int bid = (blockIdx.x % NXCD) * (NIMG * NCH * NGRP / NXCD)
                  + blockIdx.x / NXCD;
    const int g = bid % NGRP;
    const int c = (bid / NGRP) % NCH;
    const int n = bid / (NGRP * NCH);
    const int oy0 = g * RG;

    const int4 box = detections[n];
    const float bh = (float)(box.w - box.y);
    const float bw = (float)(box.z - box.x);
    const int   bw1 = (box.z - box.x) + 1;   // needed floats per row

    auto ysrc = [&](int oy) -> float {
        float ys = ((float)oy + 0.5f) * bh * (1.0f / OUT) - 0.5f;
        return fminf(fmaxf(ys, 0.0f), bh - 1.0f);
    };

    const int yA = (int)floorf(ysrc(oy0));               // first staged row
    const int yE = (int)floorf(ysrc(oy0 + RG - 1)) + 1;  // last staged row
    const int NR = yE - yA + 1;                          // <= 12

    const float* __restrict__ base =
        features + ((size_t)n * NCH + c) * (size_t)(IMH * IMW);

    const int tid  = threadIdx.x;
    const int wave = tid >> 6;
    const int lane = tid & 63;

    // ---- stage: float4 loads from aligned-down x, float4 LDS writes ----
    // Aligned groups covering needed cols (<= x2 <= W-1) start <= W-4: in-row.
    const int x1a = box.x & ~3;
    const int d   = box.x - x1a;                 // 0..3 LDS column shift
    const int G   = (d + bw1 + 3) >> 2;          // float4 groups per row, <=81
    const float4* __restrict__ srcv0 = reinterpret_cast<const float4*>(
        base + (size_t)(box.y + yA) * IMW + x1a);
    for (int r = wave; r < NR; r += NW) {
        const float4* __restrict__ srcv = srcv0 + (size_t)r * (IMW / 4);
        float4* __restrict__ dst = reinterpret_cast<float4*>(&lds[r * ROWP]);
        for (int k = lane; k < G; k += 64)
            dst[k] = srcv[k];
    }
    __syncthreads();

    // ---- compute: wave w -> output row oy0+w; lane -> 4 px (float4 store) --
    const int oy = oy0 + wave;
    const float ys  = ysrc(oy);
    const float y0f = floorf(ys);
    const float wy  = ys - y0f;
    const int   r0  = (int)y0f - yA;             // in [0, NR-2]
    const float* __restrict__ l0 = lds + r0 * ROWP + d;
    const float* __restrict__ l1 = l0 + ROWP;

    if (lane < OUT / 4) {                        // lanes 0..55
        const int ox0 = lane * 4;
        float res[4];
#pragma unroll
        for (int j = 0; j < 4; ++j) {
            float xs = ((float)(ox0 + j) + 0.5f) * bw * (1.0f / OUT) - 0.5f;
            xs = fminf(fmaxf(xs, 0.0f), bw - 1.0f);
            const float x0f = floorf(xs);
            const float wx  = xs - x0f;
            const int   ix  = (int)x0f;          // 0..bw-1; ix+1 <= bw staged
            const float v00 = l0[ix], v01 = l0[ix + 1];
            const float v10 = l1[ix], v11 = l1[ix + 1];
            const float top = v00 + (v01 - v00) * wx;
            const float bot = v10 + (v11 - v10) * wx;
            res[j] = top + (bot - top) * wy;
        }
        out[(((size_t)n * NCH + c) * OUT + oy) * (OUT / 4) + lane] =
            make_float4(res[0], res[1], res[2], res[3]);
    }
}

extern "C" void kernel_launch(void* const* d_in, const int* in_sizes, int n_in,
                              void* d_out, int out_size, void* d_ws, size_t ws_size,
                              hipStream_t stream) {
    const float* features   = (const float*)d_in[0];
    const int4*  detections = (const int4*)d_in[1];
    float4*      out        = (float4*)d_out;

    const int grid = NIMG * NCH * NGRP;   // 64*3*28 = 5376 = 8*672
    roi_lds8_kernel<<<grid, 512, 0, stream>>>(features, detections, out);
}

// Round 7
// 19.859 us; speedup vs baseline: 1.5936x; 1.0442x over previous
//
#include <hip/hip_runtime.h>

#define OUT 224
#define NIMG 64
#define NCH 3
#define IMH 1080
#define IMW 1920

#define RG 8               // output rows per block (one per wave)
#define NGRP (OUT / RG)    // 28 row-groups
#define NW 8               // waves per block (512 threads)
#define ROWP 328           // LDS row pitch (floats): <=324 needed, mult of 4
#define MAXR 13            // max staged rows: ceil(7*319/224)+2 = 12, padded
#define NXCD 8

__global__ __launch_bounds__(512) void roi_lds8_s1_kernel(
    const float* __restrict__ features,   // [N,C,H,W]
    const int4*  __restrict__ detections, // [N] {x1,y1,x2,y2}
    float*       __restrict__ out)        // [N,C,OUT,OUT]
{
    __shared__ float lds[MAXR * ROWP];

    // chunked XCD swizzle: grid = 5376 = 8 * 672 exactly
    const int bid = (blockIdx.x % NXCD) * (NIMG * NCH * NGRP / NXCD)
                  + blockIdx.x / NXCD;
    const int g = bid % NGRP;
    const int c = (bid / NGRP) % NCH;
    const int n = bid / (NGRP * NCH);
    const int oy0 = g * RG;

    const int4 box = detections[n];
    const float bh = (float)(box.w - box.y);
    const float bw = (float)(box.z - box.x);
    const int   bw1 = (box.z - box.x) + 1;   // needed floats per row

    auto ysrc = [&](int oy) -> float {
        float ys = ((float)oy + 0.5f) * bh * (1.0f / OUT) - 0.5f;
        return fminf(fmaxf(ys, 0.0f), bh - 1.0f);
    };

    const int yA = (int)floorf(ysrc(oy0));               // first staged row
    const int yE = (int)floorf(ysrc(oy0 + RG - 1)) + 1;  // last staged row
    const int NR = yE - yA + 1;                          // <= 12

    const float* __restrict__ base =
        features + ((size_t)n * NCH + c) * (size_t)(IMH * IMW);

    const int tid  = threadIdx.x;
    const int wave = tid >> 6;
    const int lane = tid & 63;

    // ---- stage: float4 loads from aligned-down x, float4 LDS writes ----
    // Aligned groups covering needed cols (<= x2 <= W-1) start <= W-4: in-row.
    const int x1a = box.x & ~3;
    const int d   = box.x - x1a;                 // 0..3 LDS column shift
    const int G   = (d + bw1 + 3) >> 2;          // float4 groups per row, <=81
    const float4* __restrict__ srcv0 = reinterpret_cast<const float4*>(
        base + (size_t)(box.y + yA) * IMW + x1a);
    for (int r = wave; r < NR; r += NW) {
        const float4* __restrict__ srcv = srcv0 + (size_t)r * (IMW / 4);
        float4* __restrict__ dst = reinterpret_cast<float4*>(&lds[r * ROWP]);
        for (int k = lane; k < G; k += 64)
            dst[k] = srcv[k];
    }
    __syncthreads();

    // ---- compute: wave w -> output row oy0+w; lane stride-1 over x ----
    // Adjacent lanes step bw/224 <= 1.43 floats in LDS -> <=2 lanes/bank
    // (free, m136) + broadcasts. Kills the stride-4 8-way conflict of the
    // lane->4-consecutive-px mapping.
    const int oy = oy0 + wave;
    const float ys  = ysrc(oy);
    const float y0f = floorf(ys);
    const float wy  = ys - y0f;
    const int   r0  = (int)y0f - yA;             // in [0, NR-2]
    const float* __restrict__ l0 = lds + r0 * ROWP + d;
    const float* __restrict__ l1 = l0 + ROWP;

    float* __restrict__ orow =
        out + (((size_t)n * NCH + c) * OUT + oy) * OUT;

#pragma unroll
    for (int k = 0; k < 4; ++k) {
        const int ox = (k << 6) + lane;          // stride-1 across lanes
        if (ox < OUT) {
            float xs = ((float)ox + 0.5f) * bw * (1.0f / OUT) - 0.5f;
            xs = fminf(fmaxf(xs, 0.0f), bw - 1.0f);
            const float x0f = floorf(xs);
            const float wx  = xs - x0f;
            const int   ix  = (int)x0f;          // 0..bw-1; ix+1 <= bw staged
            const float v00 = l0[ix], v01 = l0[ix + 1];
            const float v10 = l1[ix], v11 = l1[ix + 1];
            const float top = v00 + (v01 - v00) * wx;
            const float bot = v10 + (v11 - v10) * wx;
            orow[ox] = top + (bot - top) * wy;
        }
    }
}

extern "C" void kernel_launch(void* const* d_in, const int* in_sizes, int n_in,
                              void* d_out, int out_size, void* d_ws, size_t ws_size,
                              hipStream_t stream) {
    const float* features   = (const float*)d_in[0];
    const int4*  detections = (const int4*)d_in[1];
    float*       out        = (float*)d_out;

    const int grid = NIMG * NCH * NGRP;   // 64*3*28 = 5376 = 8*672
    roi_lds8_s1_kernel<<<grid, 512, 0, stream>>>(features, detections, out);
}

// Round 8
// 19.035 us; speedup vs baseline: 1.6625x; 1.0433x over previous
//
#include <hip/hip_runtime.h>

#define OUT 224
#define NIMG 64
#define NCH 3
#define IMH 1080
#define IMW 1920

#define RG 16              // output rows per block (2 per wave)
#define NGRP (OUT / RG)    // 14 row-groups
#define NW 8               // waves per block (512 threads)
#define ROWP 328           // LDS row pitch (floats): <=324 needed, mult of 4
#define MAXR 25            // max staged rows: 16*319/224 + 2 = 24.8 -> 25
#define NXCD 8

__global__ __launch_bounds__(512) void roi_lds16_kernel(
    const float* __restrict__ features,   // [N,C,H,W]
    const int4*  __restrict__ detections, // [N] {x1,y1,x2,y2}
    float*       __restrict__ out)        // [N,C,OUT,OUT]
{
    __shared__ float lds[MAXR * ROWP];

    // chunked XCD swizzle: grid = 2688 = 8 * 336 exactly
    const int bid = (blockIdx.x % NXCD) * (NIMG * NCH * NGRP / NXCD)
                  + blockIdx.x / NXCD;
    const int g = bid % NGRP;
    const int c = (bid / NGRP) % NCH;
    const int n = bid / (NGRP * NCH);
    const int oy0 = g * RG;

    const int4 box = detections[n];
    const float bh = (float)(box.w - box.y);
    const float bw = (float)(box.z - box.x);
    const int   bw1 = (box.z - box.x) + 1;   // needed floats per row

    auto ysrc = [&](int oy) -> float {
        float ys = ((float)oy + 0.5f) * bh * (1.0f / OUT) - 0.5f;
        return fminf(fmaxf(ys, 0.0f), bh - 1.0f);
    };

    const int yA = (int)floorf(ysrc(oy0));               // first staged row
    const int yE = (int)floorf(ysrc(oy0 + RG - 1)) + 1;  // last staged row
    const int NR = yE - yA + 1;                          // <= 25

    const float* __restrict__ base =
        features + ((size_t)n * NCH + c) * (size_t)(IMH * IMW);

    const int tid  = threadIdx.x;
    const int wave = tid >> 6;
    const int lane = tid & 63;

    // ---- stage: float4 loads from aligned-down x, float4 LDS writes ----
    const int x1a = box.x & ~3;
    const int d   = box.x - x1a;                 // 0..3 LDS column shift
    const int G   = (d + bw1 + 3) >> 2;          // float4 groups per row, <=81
    const float4* __restrict__ srcv0 = reinterpret_cast<const float4*>(
        base + (size_t)(box.y + yA) * IMW + x1a);
    for (int r = wave; r < NR; r += NW) {
        const float4* __restrict__ srcv = srcv0 + (size_t)r * (IMW / 4);
        float4* __restrict__ dst = reinterpret_cast<float4*>(&lds[r * ROWP]);
        for (int k = lane; k < G; k += 64)
            dst[k] = srcv[k];
    }
    __syncthreads();

    // ---- compute: wave w -> output rows oy0+w and oy0+w+8 ----
#pragma unroll
    for (int rr = 0; rr < RG / NW; ++rr) {
        const int oy = oy0 + wave + rr * NW;
        const float ys  = ysrc(oy);
        const float y0f = floorf(ys);
        const float wy  = ys - y0f;
        const int   r0  = (int)y0f - yA;         // in [0, NR-2]
        const float* __restrict__ l0 = lds + r0 * ROWP + d;
        const float* __restrict__ l1 = l0 + ROWP;

        float* __restrict__ orow =
            out + (((size_t)n * NCH + c) * OUT + oy) * OUT;

#pragma unroll
        for (int k = 0; k < 4; ++k) {
            const int ox = (k << 6) + lane;      // stride-1 across lanes
            if (ox < OUT) {
                float xs = ((float)ox + 0.5f) * bw * (1.0f / OUT) - 0.5f;
                xs = fminf(fmaxf(xs, 0.0f), bw - 1.0f);
                const float x0f = floorf(xs);
                const float wx  = xs - x0f;
                const int   ix  = (int)x0f;      // 0..bw-1; ix+1 <= bw staged
                const float v00 = l0[ix], v01 = l0[ix + 1];
                const float v10 = l1[ix], v11 = l1[ix + 1];
                const float top = v00 + (v01 - v00) * wx;
                const float bot = v10 + (v11 - v10) * wx;
                orow[ox] = top + (bot - top) * wy;
            }
        }
    }
}

extern "C" void kernel_launch(void* const* d_in, const int* in_sizes, int n_in,
                              void* d_out, int out_size, void* d_ws, size_t ws_size,
                              hipStream_t stream) {
    const float* features   = (const float*)d_in[0];
    const int4*  detections = (const int4*)d_in[1];
    float*       out        = (float*)d_out;

    const int grid = NIMG * NCH * NGRP;   // 64*3*14 = 2688 = 8*336
    roi_lds16_kernel<<<grid, 512, 0, stream>>>(features, detections, out);
}

// Round 9
// 17.311 us; speedup vs baseline: 1.8281x; 1.0996x over previous
//
#include <hip/hip_runtime.h>

#define OUT 224
#define NIMG 64
#define NCH 3
#define IMH 1080
#define IMW 1920

#define RG 8               // output rows per block (2 per wave)
#define NGRP (OUT / RG)    // 28 row-groups
#define NW 4               // waves per block (256 threads)
#define ROWP 328           // LDS row pitch (floats)
#define MAXR 13            // max staged rows (<=12)
#define NXCD 8

__global__ __launch_bounds__(256) void roi_lds8_nt_kernel(
    const float* __restrict__ features,   // [N,C,H,W]
    const int4*  __restrict__ detections, // [N] {x1,y1,x2,y2}
    float*       __restrict__ out)        // [N,C,OUT,OUT]
{
    __shared__ float lds[MAXR * ROWP];

    // chunked XCD swizzle: grid = 5376 = 8 * 672 exactly
    const int bid = (blockIdx.x % NXCD) * (NIMG * NCH * NGRP / NXCD)
                  + blockIdx.x / NXCD;
    const int g = bid % NGRP;
    const int c = (bid / NGRP) % NCH;
    const int n = bid / (NGRP * NCH);
    const int oy0 = g * RG;

    const int4 box = detections[n];
    const float bh = (float)(box.w - box.y);
    const float bw = (float)(box.z - box.x);
    const int   bw1 = (box.z - box.x) + 1;   // needed floats per row

    auto ysrc = [&](int oy) -> float {
        float ys = ((float)oy + 0.5f) * bh * (1.0f / OUT) - 0.5f;
        return fminf(fmaxf(ys, 0.0f), bh - 1.0f);
    };

    const int yA = (int)floorf(ysrc(oy0));               // first staged row
    const int yE = (int)floorf(ysrc(oy0 + RG - 1)) + 1;  // last staged row
    const int NR = yE - yA + 1;                          // <= 12

    const float* __restrict__ base =
        features + ((size_t)n * NCH + c) * (size_t)(IMH * IMW);

    const int tid  = threadIdx.x;
    const int wave = tid >> 6;
    const int lane = tid & 63;

    // ---- stage: float4 loads from aligned-down x, float4 LDS writes ----
    const int x1a = box.x & ~3;
    const int d   = box.x - x1a;                 // 0..3 LDS column shift
    const int G   = (d + bw1 + 3) >> 2;          // float4 groups per row, <=81
    const float4* __restrict__ srcv0 = reinterpret_cast<const float4*>(
        base + (size_t)(box.y + yA) * IMW + x1a);
    for (int r = wave; r < NR; r += NW) {
        const float4* __restrict__ srcv = srcv0 + (size_t)r * (IMW / 4);
        float4* __restrict__ dst = reinterpret_cast<float4*>(&lds[r * ROWP]);
        for (int k = lane; k < G; k += 64)
            dst[k] = srcv[k];
    }
    __syncthreads();

    // ---- compute: wave w -> output rows oy0+w and oy0+w+4 ----
#pragma unroll
    for (int rr = 0; rr < RG / NW; ++rr) {
        const int oy = oy0 + wave + rr * NW;
        const float ys  = ysrc(oy);
        const float y0f = floorf(ys);
        const float wy  = ys - y0f;
        const int   r0  = (int)y0f - yA;         // in [0, NR-2]
        const float* __restrict__ l0 = lds + r0 * ROWP + d;
        const float* __restrict__ l1 = l0 + ROWP;

        float* __restrict__ orow =
            out + (((size_t)n * NCH + c) * OUT + oy) * OUT;

#pragma unroll
        for (int k = 0; k < 4; ++k) {
            const int ox = (k << 6) + lane;      // stride-1 across lanes
            if (ox < OUT) {
                float xs = ((float)ox + 0.5f) * bw * (1.0f / OUT) - 0.5f;
                xs = fminf(fmaxf(xs, 0.0f), bw - 1.0f);
                const float x0f = floorf(xs);
                const float wx  = xs - x0f;
                const int   ix  = (int)x0f;      // 0..bw-1; ix+1 <= bw staged
                const float v00 = l0[ix], v01 = l0[ix + 1];
                const float v10 = l1[ix], v11 = l1[ix + 1];
                const float top = v00 + (v01 - v00) * wx;
                const float bot = v10 + (v11 - v10) * wx;
                // output is never re-read: bypass L2, keep it for crop rows
                __builtin_nontemporal_store(top + (bot - top) * wy, &orow[ox]);
            }
        }
    }
}

extern "C" void kernel_launch(void* const* d_in, const int* in_sizes, int n_in,
                              void* d_out, int out_size, void* d_ws, size_t ws_size,
                              hipStream_t stream) {
    const float* features   = (const float*)d_in[0];
    const int4*  detections = (const int4*)d_in[1];
    float*       out        = (float*)d_out;

    const int grid = NIMG * NCH * NGRP;   // 64*3*28 = 5376 = 8*672
    roi_lds8_nt_kernel<<<grid, 256, 0, stream>>>(features, detections, out);
}